// Round 1
// baseline (457.908 us; speedup 1.0000x reference)
//
#include <hip/hip_runtime.h>

#define NN    50000
#define DD    128
#define RR    3
#define EE    800000
#define OUTD  64
#define BKT   128                 // nodes per bucket (dst and src binning)
#define NBK   391                 // ceil(NN/BKT)
#define CAP   2560                // per-bucket edge capacity, 4B dst-entries
#define CAPB  2560                // per-bucket edge capacity, 2B src-entries
#define CHUNK 2048                // edges per bin block
#define NCH   391                 // ceil(EE/CHUNK)
#define SETUPB 6250               // NN*DD/4/256 setup blocks
#define ALPHA_ 0.5f
#define SLOPE_ 0.01f
#define BETA1_ 0.6931471805599453f   // log(2)
#define BETA2_ 0.4054651081081644f   // log(1.5)

typedef __attribute__((ext_vector_type(8))) short short8;   // 8 bf16 = 4 VGPRs
typedef __attribute__((ext_vector_type(4))) float f32x4;

__device__ __forceinline__ unsigned short f2b(float f) {   // fp32 -> bf16 RNE
    unsigned int u = __builtin_bit_cast(unsigned int, f);
    u += 0x7FFFu + ((u >> 16) & 1u);
    return (unsigned short)(u >> 16);
}
__device__ __forceinline__ unsigned int pack2(float lo, float hi) {
    return (unsigned int)f2b(lo) | ((unsigned int)f2b(hi) << 16);
}
__device__ __forceinline__ float blo(unsigned int w) { return __builtin_bit_cast(float, w << 16); }
__device__ __forceinline__ float bhi(unsigned int w) { return __builtin_bit_cast(float, w & 0xFFFF0000u); }

// ---------------- binning: phase-split LDS bucket-sort (A: by dst>>7, B: by src>>7) ----------------
__global__ __launch_bounds__(256) void bin_kernel(
    const int* __restrict__ src, const int* __restrict__ dst,
    int* __restrict__ bcnt_d, int* __restrict__ bcnt_s,
    int* __restrict__ pairs_d, unsigned short* __restrict__ pairs_s)
{
    __shared__ int hist[NBK];
    __shared__ int lbase[NBK];
    __shared__ int gdelta[NBK];
    __shared__ int lcur[NBK];
    __shared__ unsigned int staging[CHUNK];
    unsigned short* staging16 = (unsigned short*)staging;
    const int tid = threadIdx.x;
    const int blk = blockIdx.x;
    const int phase = (blk >= RR * NCH);
    const int rb = phase ? blk - RR * NCH : blk;
    const int r = rb / NCH;
    const int chunk = rb % NCH;
    const int e0 = chunk * CHUNK;
    const int n = min(CHUNK, EE - e0);
    const int* sp = src + (size_t)r * EE + e0;
    const int* dp = dst + (size_t)r * EE + e0;
    const int* kp = phase ? sp : dp;         // key stream for this phase

    for (int i = tid; i < NBK; i += 256) hist[i] = 0;
    __syncthreads();
    for (int i = tid; i < n; i += 256)
        atomicAdd(&hist[kp[i] >> 7], 1);
    __syncthreads();
    if (tid < 64) {
        int carry = 0;
        for (int c0 = 0; c0 < NBK; c0 += 64) {
            const int idx = c0 + tid;
            const int v = (idx < NBK) ? hist[idx] : 0;
            int incl = v;
            #pragma unroll
            for (int d = 1; d < 64; d <<= 1) {
                const int t = __shfl_up(incl, d, 64);
                if (tid >= d) incl += t;
            }
            if (idx < NBK) lbase[idx] = carry + incl - v;
            carry += __shfl(incl, 63, 64);
        }
    }
    __syncthreads();
    if (!phase) {
        for (int b = tid; b < NBK; b += 256) {
            lcur[b] = lbase[b];
            const int h = hist[b];
            if (h > 0) {
                const int gstart = (r * NBK + b) * CAP + atomicAdd(&bcnt_d[r * NBK + b], h);
                gdelta[b] = gstart - lbase[b];
            }
        }
        __syncthreads();
        for (int i = tid; i < n; i += 256) {
            const int d = dp[i];
            const int b = d >> 7;
            const int pos = atomicAdd(&lcur[b], 1);
            staging[pos] = (unsigned int)sp[i] | ((unsigned int)(d & 127) << 16)
                         | ((unsigned int)b << 23);
        }
        __syncthreads();
        for (int j = tid; j < n; j += 256) {
            const unsigned int v = staging[j];
            const int b = v >> 23;
            const int gi = gdelta[b] + j;
            const int lo = gi - (r * NBK + b) * CAP;
            if (lo < CAP) pairs_d[gi] = (int)(v & 0x7FFFFF);
        }
    } else {
        for (int b = tid; b < NBK; b += 256) {
            lcur[b] = lbase[b];
            const int h = hist[b];
            if (h > 0) {
                const int gstart = (r * NBK + b) * CAPB + atomicAdd(&bcnt_s[r * NBK + b], h);
                gdelta[b] = gstart - lbase[b];
            }
        }
        __syncthreads();
        for (int i = tid; i < n; i += 256) {
            const int s = sp[i];
            const int b = s >> 7;
            const int pos = atomicAdd(&lcur[b], 1);
            staging16[pos] = (unsigned short)((b << 7) | (s & 127));
        }
        __syncthreads();
        for (int j = tid; j < n; j += 256) {
            const unsigned short v = staging16[j];
            const int b = v >> 7;
            const int gi = gdelta[b] + j;
            const int lo = gi - (r * NBK + b) * CAPB;
            if (lo < CAPB) pairs_s[gi] = v;
        }
    }
}

// ---------------- merged: dego count (low blocks) + x cast / W' prep (high blocks) ----------------
__global__ __launch_bounds__(256) void dego_setup_kernel(
    const unsigned short* __restrict__ pairs_s, const int* __restrict__ bcnt_s,
    float* __restrict__ dego_r,
    const float* __restrict__ x, unsigned short* __restrict__ xb,
    const float* __restrict__ W1, const float* __restrict__ W2,
    const float* __restrict__ Wlin, unsigned short* __restrict__ Wt1,
    unsigned short* __restrict__ Wt2, unsigned short* __restrict__ WlT)
{
    __shared__ int scnt[BKT];
    const int tid = threadIdx.x;
    const int blk = blockIdx.x;
    if (blk < RR * NBK) {
        const int n2 = min(bcnt_s[blk], CAPB);
        const unsigned short* ps = pairs_s + (size_t)blk * CAPB;
        if (tid < BKT) scnt[tid] = 0;
        __syncthreads();
        for (int i = tid; i < n2; i += 256)
            atomicAdd(&scnt[ps[i] & 127], 1);
        __syncthreads();
        if (tid < BKT) {
            const int r = blk / NBK;
            const int g = (blk % NBK) * BKT + tid;
            if (g < NN)
                dego_r[r * NN + g] = rsqrtf((float)max(scnt[tid], 1));
        }
    } else {
        const int i = (blk - RR * NBK) * 256 + tid;   // 0 .. NN*DD/4-1
        {
            const float4 v = ((const float4*)x)[i];
            ushort4 o;
            o.x = f2b(v.x); o.y = f2b(v.y); o.z = f2b(v.z); o.w = f2b(v.w);
            ((ushort4*)xb)[i] = o;
        }
        if (i < RR * DD * DD) {
            const int r = i >> 14, rem = i & 16383, nn = rem >> 7, k = rem & 127;
            const float diag = (k == nn) ? 1.0f : 0.0f;
            const float w1 = W1[r * DD * DD + k * DD + nn];
            Wt1[i] = f2b(BETA1_ * w1 + diag * (1.0f - BETA1_));
            const float w2 = W2[r * DD * DD + k * DD + nn];
            Wt2[i] = f2b((BETA2_ * w2 + diag * (1.0f - BETA2_)) * (1.0f / 3.0f));
        } else if (i < RR * DD * DD + OUTD * DD) {
            const int j = i - RR * DD * DD;
            const int nn = j >> 7, k = j & 127;
            WlT[j] = f2b(Wlin[k * OUTD + nn]);
        }
    }
}

// ---------------- per-bucket counting sort (in place) -> weighted CSR + degi ----------------
__global__ __launch_bounds__(256) void sort_kernel(
    int* __restrict__ pairs_d, const int* __restrict__ bcnt_d,
    const float* __restrict__ dego_r,
    int* __restrict__ off_g, int* __restrict__ cnt_g, float* __restrict__ degi_r)
{
    __shared__ int stage[CAP];
    __shared__ int cnt[BKT];
    __shared__ int base[BKT];
    __shared__ int pos[BKT];
    const int tid = threadIdx.x;
    const int bid = blockIdx.x;              // r*NBK + b
    const int rr = bid / NBK;
    const int n = min(bcnt_d[bid], CAP);
    int* pp = pairs_d + (size_t)bid * CAP;
    const float* dego = dego_r + (size_t)rr * NN;
    if (tid < BKT) cnt[tid] = 0;
    __syncthreads();
    for (int i = tid; i < n; i += 256) {
        const int p = pp[i];
        stage[i] = p;
        atomicAdd(&cnt[p >> 16], 1);
    }
    __syncthreads();
    if (tid < 64) {
        int carry = 0;
        for (int c0 = 0; c0 < BKT; c0 += 64) {
            const int v = cnt[c0 + tid];
            int incl = v;
            #pragma unroll
            for (int d = 1; d < 64; d <<= 1) {
                const int t = __shfl_up(incl, d, 64);
                if (tid >= d) incl += t;
            }
            base[c0 + tid] = carry + incl - v;
            carry += __shfl(incl, 63, 64);
        }
    }
    __syncthreads();
    if (tid < BKT) {
        pos[tid] = base[tid];
        const int g = (bid % NBK) * BKT + tid;
        if (g < NN) {
            off_g[rr * NN + g] = bid * CAP + base[tid];
            cnt_g[rr * NN + g] = cnt[tid];
            degi_r[rr * NN + g] = rsqrtf((float)max(cnt[tid], 1));
        }
    }
    __syncthreads();
    for (int i = tid; i < n; i += 256) {
        const int p = stage[i];
        const int q = atomicAdd(&pos[p >> 16], 1);
        const int s = p & 0xFFFF;
        pp[q] = s | ((int)f2b(dego[s]) << 16);   // src + folded bf16 weight
    }
}

// ---------------- FUSED: weighted-CSR gather directly into MFMA A-frags + conv (+lin) ----------------
// 4 lanes per node (q = k-group). Thread (l15,q) gathers dims {32*ks+8*q+e}, which IS the
// 16x16x32 A-fragment layout -> no aggb round trip, no LDS transpose.
template<int LIN>
__global__ __launch_bounds__(256, 4) void fused_conv_kernel(
    const unsigned short* __restrict__ hb,   // gather table [N,128] bf16
    const unsigned short* __restrict__ xb,   // residual [N,128] bf16
    const int* __restrict__ csrw, const int* __restrict__ off_g,
    const int* __restrict__ cnt_g, const float* __restrict__ degi_r,
    const unsigned short* __restrict__ WtG,  // [R][128][128] bf16, [n][k]
    const float* __restrict__ bias,          // [R,128]
    const unsigned short* __restrict__ WlT,  // [64][128] bf16 (LIN)
    const float* __restrict__ blin,          // [64] (LIN)
    unsigned short* __restrict__ houtb,      // h1b (LIN=0)
    float* __restrict__ outf)                // out [N,64] (LIN=1)
{
    __shared__ unsigned short WtL[DD * 136];   // 34816 B, stride 136 bf16 (17 uint4)
    uint4* WtL4 = (uint4*)WtL;
    const int tid  = threadIdx.x;
    const int wave = tid >> 6;
    const int lane = tid & 63;
    const int l15  = lane & 15;
    const int q    = lane >> 4;                // 0..3  (k-group)
    const int blockRow = blockIdx.x * 64;
    const int row0 = blockRow + wave * 16;
    const int arow = min(row0 + l15, NN - 1);  // A-frag row (clamped)

    const uint4* hb4 = (const uint4*)hb;
    const uint4* xb4 = (const uint4*)xb;

    f32x4 o[8];
    if (LIN) {
        #pragma unroll
        for (int ct = 0; ct < 8; ++ct) {
            const int col = ct * 16 + l15;
            const float bv = (bias[col] + bias[DD + col] + bias[2 * DD + col]) * (1.0f / 3.0f);
            o[ct] = (f32x4){bv, bv, bv, bv};
        }
    } else {
        #pragma unroll
        for (int ct = 0; ct < 8; ++ct) o[ct] = (f32x4){0.f, 0.f, 0.f, 0.f};
    }

    for (int r = 0; r < RR; ++r) {
        __syncthreads();                       // previous relation done reading WtL
        const uint4* wg = (const uint4*)(WtG + (size_t)r * DD * DD);
        for (int i = tid; i < DD * 16; i += 256)
            WtL4[(i >> 4) * 17 + (i & 15)] = wg[i];

        // ---- gather-accumulate directly in A-frag layout ----
        const int gi = r * NN + arow;
        const int j0 = off_g[gi];
        const int j1 = j0 + cnt_g[gi];
        float acc[4][8];
        #pragma unroll
        for (int ks = 0; ks < 4; ++ks)
            #pragma unroll
            for (int e = 0; e < 8; ++e) acc[ks][e] = 0.f;

        int j = j0;
        for (; j + 2 <= j1; j += 2) {
            const unsigned int p0 = csrw[j], p1 = csrw[j + 1];
            const float n0 = bhi(p0), n1 = bhi(p1);
            const uint4* r0p = hb4 + (size_t)(p0 & 0xFFFF) * 16 + q;
            const uint4* r1p = hb4 + (size_t)(p1 & 0xFFFF) * 16 + q;
            uint4 u0[4], u1[4];
            #pragma unroll
            for (int ks = 0; ks < 4; ++ks) { u0[ks] = r0p[ks * 4]; u1[ks] = r1p[ks * 4]; }
            #pragma unroll
            for (int ks = 0; ks < 4; ++ks) {
                acc[ks][0] += blo(u0[ks].x) * n0 + blo(u1[ks].x) * n1;
                acc[ks][1] += bhi(u0[ks].x) * n0 + bhi(u1[ks].x) * n1;
                acc[ks][2] += blo(u0[ks].y) * n0 + blo(u1[ks].y) * n1;
                acc[ks][3] += bhi(u0[ks].y) * n0 + bhi(u1[ks].y) * n1;
                acc[ks][4] += blo(u0[ks].z) * n0 + blo(u1[ks].z) * n1;
                acc[ks][5] += bhi(u0[ks].z) * n0 + bhi(u1[ks].z) * n1;
                acc[ks][6] += blo(u0[ks].w) * n0 + blo(u1[ks].w) * n1;
                acc[ks][7] += bhi(u0[ks].w) * n0 + bhi(u1[ks].w) * n1;
            }
        }
        if (j < j1) {
            const unsigned int p0 = csrw[j];
            const float n0 = bhi(p0);
            const uint4* r0p = hb4 + (size_t)(p0 & 0xFFFF) * 16 + q;
            uint4 u0[4];
            #pragma unroll
            for (int ks = 0; ks < 4; ++ks) u0[ks] = r0p[ks * 4];
            #pragma unroll
            for (int ks = 0; ks < 4; ++ks) {
                acc[ks][0] += blo(u0[ks].x) * n0;
                acc[ks][1] += bhi(u0[ks].x) * n0;
                acc[ks][2] += blo(u0[ks].y) * n0;
                acc[ks][3] += bhi(u0[ks].y) * n0;
                acc[ks][4] += blo(u0[ks].z) * n0;
                acc[ks][5] += bhi(u0[ks].z) * n0;
                acc[ks][6] += blo(u0[ks].w) * n0;
                acc[ks][7] += bhi(u0[ks].w) * n0;
            }
        }

        // ---- residual blend + pack to A-frags ----
        const float nd = degi_r[gi] * (1.0f - ALPHA_);
        short8 a[4];
        #pragma unroll
        for (int ks = 0; ks < 4; ++ks) {
            const uint4 xq = xb4[(size_t)arow * 16 + ks * 4 + q];
            uint4 pa;
            pa.x = pack2(acc[ks][0] * nd + ALPHA_ * blo(xq.x), acc[ks][1] * nd + ALPHA_ * bhi(xq.x));
            pa.y = pack2(acc[ks][2] * nd + ALPHA_ * blo(xq.y), acc[ks][3] * nd + ALPHA_ * bhi(xq.y));
            pa.z = pack2(acc[ks][4] * nd + ALPHA_ * blo(xq.z), acc[ks][5] * nd + ALPHA_ * bhi(xq.z));
            pa.w = pack2(acc[ks][6] * nd + ALPHA_ * blo(xq.w), acc[ks][7] * nd + ALPHA_ * bhi(xq.w));
            a[ks] = __builtin_bit_cast(short8, pa);
        }
        __syncthreads();                       // WtL staged & visible

        // ---- MFMA: rst_r @ W'_r ----
        #pragma unroll
        for (int ct = 0; ct < 8; ++ct) {
            f32x4 acc2;
            if (LIN) {
                acc2 = o[ct];
            } else {
                const float bv = bias[r * DD + ct * 16 + l15];
                acc2 = (f32x4){bv, bv, bv, bv};
            }
            const int nrow = ct * 16 + l15;
            #pragma unroll
            for (int ks = 0; ks < 4; ++ks) {
                const short8 b = __builtin_bit_cast(short8, WtL4[nrow * 17 + ks * 4 + q]);
                acc2 = __builtin_amdgcn_mfma_f32_16x16x32_bf16(a[ks], b, acc2, 0, 0, 0);
            }
            if (LIN) {
                o[ct] = acc2;
            } else {
                #pragma unroll
                for (int e = 0; e < 4; ++e) {
                    float v = acc2[e];
                    v = v >= 0.f ? v : SLOPE_ * v;
                    o[ct][e] += v * (1.0f / 3.0f);
                }
            }
        }
    }

    __syncthreads();
    unsigned short* tile = WtL;                // rows 0..63, stride 136
    #pragma unroll
    for (int ct = 0; ct < 8; ++ct) {
        const int col = ct * 16 + l15;
        #pragma unroll
        for (int e = 0; e < 4; ++e) {
            const int lrow = wave * 16 + q * 4 + e;
            tile[lrow * 136 + col] = f2b(o[ct][e]);
        }
    }
    if (LIN) {
        uint4* wl4 = WtL4 + 64 * 17;
        const uint4* wg = (const uint4*)WlT;
        for (int i = tid; i < OUTD * 16; i += 256)
            wl4[(i >> 4) * 17 + (i & 15)] = wg[i];
    }
    __syncthreads();

    if (!LIN) {
        for (int i = tid; i < 64 * 16; i += 256) {
            const int lrow = i >> 4, c = i & 15;
            const int grow = blockRow + lrow;
            if (grow < NN)
                ((uint4*)houtb)[(size_t)grow * 16 + c] = WtL4[lrow * 17 + c];
        }
    } else {
        short8 a2[4];
        const int lrow = wave * 16 + l15;
        #pragma unroll
        for (int ks = 0; ks < 4; ++ks)
            a2[ks] = __builtin_bit_cast(short8, WtL4[lrow * 17 + ks * 4 + q]);
        #pragma unroll
        for (int ct = 0; ct < 4; ++ct) {
            const int col = ct * 16 + l15;
            const float bv = blin[col];
            f32x4 acc = (f32x4){bv, bv, bv, bv};
            #pragma unroll
            for (int ks = 0; ks < 4; ++ks) {
                const short8 b = __builtin_bit_cast(short8, WtL4[(64 + col) * 17 + ks * 4 + q]);
                acc = __builtin_amdgcn_mfma_f32_16x16x32_bf16(a2[ks], b, acc, 0, 0, 0);
            }
            #pragma unroll
            for (int e = 0; e < 4; ++e) {
                const int grow = row0 + q * 4 + e;
                if (grow < NN) outf[(size_t)grow * OUTD + col] = acc[e];
            }
        }
    }
}

extern "C" void kernel_launch(void* const* d_in, const int* in_sizes, int n_in,
                              void* d_out, int out_size, void* d_ws, size_t ws_size,
                              hipStream_t stream)
{
    const float* x    = (const float*)d_in[0];
    const int*   src  = (const int*)  d_in[1];
    const int*   dst  = (const int*)  d_in[2];
    const float* W1   = (const float*)d_in[3];
    const float* b1   = (const float*)d_in[4];
    const float* W2   = (const float*)d_in[5];
    const float* b2   = (const float*)d_in[6];
    const float* Wlin = (const float*)d_in[7];
    const float* blin = (const float*)d_in[8];
    float* out = (float*)d_out;

    // ws layout (4B units): bcnt_d[3*NBK] | bcnt_s[3*NBK] | dego_r[3N] | degi_r[3N] |
    //   off_g[3N] | cnt_g[3N] | pad[2] | pairs_d[3*NBK*CAP] | pairs_s(u16) |
    //   xb(bf16 N*D) | h1b(bf16 N*D) | aggb(unused) | Wt1 | Wt2 | WlT
    int*   bcnt_d  = (int*)d_ws;
    int*   bcnt_s  = bcnt_d + RR * NBK;
    float* dego_r  = (float*)(bcnt_s + RR * NBK);
    float* degi_r  = dego_r + RR * NN;
    int*   off_g   = (int*)(degi_r + RR * NN);
    int*   cnt_g   = off_g + RR * NN;
    int*   pairs_d = cnt_g + RR * NN + 2;    // +2 -> 16B alignment downstream
    unsigned short* pairs_s = (unsigned short*)(pairs_d + (size_t)RR * NBK * CAP);
    unsigned short* xb   = pairs_s + (size_t)RR * NBK * CAPB;
    unsigned short* h1b  = xb + (size_t)NN * DD;
    unsigned short* aggb = h1b + (size_t)NN * DD;   // unused (kept for layout stability)
    unsigned short* Wt1  = aggb + (size_t)RR * NN * DD;
    unsigned short* Wt2  = Wt1 + RR * DD * DD;
    unsigned short* WlT  = Wt2 + RR * DD * DD;

    hipMemsetAsync(bcnt_d, 0, (size_t)2 * RR * NBK * sizeof(int), stream);

    const int gemm_blocks = (NN + 63) / 64;

    // ---- graph preprocessing (once; same graph both layers) ----
    bin_kernel<<<2 * RR * NCH, 256, 0, stream>>>(src, dst, bcnt_d, bcnt_s, pairs_d, pairs_s);
    dego_setup_kernel<<<RR * NBK + SETUPB, 256, 0, stream>>>(
        pairs_s, bcnt_s, dego_r, x, xb, W1, W2, Wlin, Wt1, Wt2, WlT);
    sort_kernel<<<RR * NBK, 256, 0, stream>>>(
        pairs_d, bcnt_d, dego_r, off_g, cnt_g, degi_r);

    // ---- conv1 fused: h1b = bf16( mean_r leaky( rst_r @ W1'_r + b1_r ) ) ----
    fused_conv_kernel<0><<<gemm_blocks, 256, 0, stream>>>(
        xb, xb, pairs_d, off_g, cnt_g, degi_r, Wt1, b1, nullptr, nullptr, h1b, nullptr);

    // ---- conv2 fused (+ final linear): out = ( sum_r rst_r @ (W2'_r/3) + mean b2 ) @ Wlin + blin ----
    fused_conv_kernel<1><<<gemm_blocks, 256, 0, stream>>>(
        h1b, xb, pairs_d, off_g, cnt_g, degi_r, Wt2, b2, WlT, blin, nullptr, out);
}